// Round 6
// baseline (1818.484 us; speedup 1.0000x reference)
//
#include <hip/hip_runtime.h>
#include <cstdint>
#include <cstddef>

// ---------------------------------------------------------------------------
// EGT layer, f32.  N nodes (DIM=96, H=32, HD=3), E edges.
// edge_bulk_kernel: one edge per lane, all row state in ext_vector SSA
// registers (v32f) -- no C arrays, so nothing can be demoted to scratch.
// FFN as two outer-product passes (no dot reductions, no Wf0 transpose).
// Atomic-free aggregation via CSR bucketing.
// ---------------------------------------------------------------------------

typedef float v32f __attribute__((ext_vector_type(32)));

__device__ __forceinline__ float vsum32(v32f x) {
    float a0 = x[0] + x[16],  a1 = x[1] + x[17],  a2 = x[2] + x[18],  a3 = x[3] + x[19];
    float a4 = x[4] + x[20],  a5 = x[5] + x[21],  a6 = x[6] + x[22],  a7 = x[7] + x[23];
    float a8 = x[8] + x[24],  a9 = x[9] + x[25],  a10 = x[10] + x[26], a11 = x[11] + x[27];
    float a12 = x[12] + x[28], a13 = x[13] + x[29], a14 = x[14] + x[30], a15 = x[15] + x[31];
    a0 += a8; a1 += a9; a2 += a10; a3 += a11;
    a4 += a12; a5 += a13; a6 += a14; a7 += a15;
    a0 += a4; a1 += a5; a2 += a6; a3 += a7;
    a0 += a2; a1 += a3;
    return a0 + a1;
}

__device__ __forceinline__ float red32(float v) {
    #pragma unroll
    for (int m = 16; m >= 1; m >>= 1) v += __shfl_xor(v, m, 64);
    return v;
}

// ---------------- row LayerNorm over D=96 ----------------
__global__ __launch_bounds__(256) void ln96_kernel(
    const float* __restrict__ x, const float* __restrict__ g,
    const float* __restrict__ b, float* __restrict__ y, int M)
{
    int lane = threadIdx.x & 31;
    int grp  = threadIdx.x >> 5;
    int r = blockIdx.x * 8 + grp;
    if (r >= M) return;
    const float* xr = x + (size_t)r * 96;
    float a0 = xr[lane], a1 = xr[lane + 32], a2 = xr[lane + 64];
    float mu = red32(a0 + a1 + a2) * (1.f / 96.f);
    float d0 = a0 - mu, d1 = a1 - mu, d2 = a2 - mu;
    float var = red32(d0 * d0 + d1 * d1 + d2 * d2) * (1.f / 96.f);
    float rs = rsqrtf(var + 1e-5f);
    float* yr = y + (size_t)r * 96;
    yr[lane]      = d0 * rs * g[lane]      + b[lane];
    yr[lane + 32] = d1 * rs * g[lane + 32] + b[lane + 32];
    yr[lane + 64] = d2 * rs * g[lane + 64] + b[lane + 64];
}

// ---------------- generic small-N GEMM: C[M,*] = A[M,K] @ B[K,*] + bias -----
template<int RELU, int RES>
__global__ __launch_bounds__(192) void gemm_kernel(
    const float* __restrict__ A, int lda,
    const float* __restrict__ B, int ldb,
    const float* __restrict__ bias,
    const float* __restrict__ resid,
    const float* __restrict__ wptr,
    float* __restrict__ C, int ldc, int n0,
    int M, int K)
{
    __shared__ float sA[32 * 68];
    __shared__ float sB[32 * 48];
    const int tid = threadIdx.x;
    const int tx = tid % 12;
    const int ty = tid / 12;
    const int m0 = blockIdx.x * 64;
    const int nb = blockIdx.y * 48;
    float acc[4][4] = {};

    for (int kc = 0; kc < K; kc += 32) {
        for (int idx = tid; idx < 64 * 32; idx += 192) {
            int m = idx >> 5, k = idx & 31;
            int row = m0 + m;
            sA[k * 68 + m] = (row < M) ? A[(size_t)row * lda + kc + k] : 0.f;
        }
        for (int idx = tid; idx < 32 * 48; idx += 192) {
            int k = idx / 48, n = idx - k * 48;
            sB[idx] = B[(size_t)(kc + k) * ldb + nb + n];
        }
        __syncthreads();
        #pragma unroll
        for (int k = 0; k < 32; k++) {
            float4 av = *(const float4*)&sA[k * 68 + ty * 4];
            float4 bv = *(const float4*)&sB[k * 48 + tx * 4];
            float a4[4] = {av.x, av.y, av.z, av.w};
            float b4[4] = {bv.x, bv.y, bv.z, bv.w};
            #pragma unroll
            for (int i = 0; i < 4; i++)
                #pragma unroll
                for (int j = 0; j < 4; j++)
                    acc[i][j] += a4[i] * b4[j];
        }
        __syncthreads();
    }

    float scale = 1.f;
    if (RES) scale = wptr ? (1.f + wptr[0]) : 1.f;
    #pragma unroll
    for (int i = 0; i < 4; i++) {
        int row = m0 + ty * 4 + i;
        if (row >= M) continue;
        #pragma unroll
        for (int j = 0; j < 4; j++) {
            int col = nb + tx * 4 + j;
            float v = acc[i][j] + bias[col];
            if (RELU) v = fmaxf(v, 0.f);
            if (RES) v += scale * resid[(size_t)row * ldc + n0 + col];
            C[(size_t)row * ldc + n0 + col] = v;
        }
    }
}

// ---------------- CSR bucketing ----------------
__global__ __launch_bounds__(256) void count_kernel(
    const int* __restrict__ dst, int* __restrict__ cnt, int E)
{
    int i = blockIdx.x * 256 + threadIdx.x;
    if (i < E) atomicAdd(&cnt[dst[i]], 1);
}

__global__ __launch_bounds__(1024) void scan_kernel(
    const int* __restrict__ cnt, int* __restrict__ off, int* __restrict__ cur, int N)
{
    __shared__ int s[1024];
    const int tid = threadIdx.x;
    const int chunk = (N + 1023) >> 10;
    const int lo = tid * chunk;
    const int hi = min(lo + chunk, N);
    int sum = 0;
    for (int i = lo; i < hi; i++) sum += cnt[i];
    s[tid] = sum;
    __syncthreads();
    for (int d = 1; d < 1024; d <<= 1) {
        int v = (tid >= d) ? s[tid - d] : 0;
        __syncthreads();
        s[tid] += v;
        __syncthreads();
    }
    int base = (tid == 0) ? 0 : s[tid - 1];
    for (int i = lo; i < hi; i++) {
        off[i] = base; cur[i] = base;
        base += cnt[i];
    }
}

__global__ __launch_bounds__(256) void scatter_kernel(
    const int* __restrict__ dst, int* __restrict__ cur,
    int* __restrict__ eidx, int E)
{
    int i = blockIdx.x * 256 + threadIdx.x;
    if (i < E) {
        int p = atomicAdd(&cur[dst[i]], 1);
        eidx[p] = i;
    }
}

// ---------------- score: qk[e][h] = 0.5 * <k[src][h], q[dst][h]> -----------
__global__ __launch_bounds__(256) void score_kernel(
    const float* __restrict__ qkv, const int* __restrict__ src,
    const int* __restrict__ dst, float* __restrict__ qk, int E)
{
    __shared__ float sQ[8][96], sK[8][96];
    const int lane = threadIdx.x & 31;
    const int grp  = threadIdx.x >> 5;
    long long e = (long long)blockIdx.x * 8 + grp;
    if (e >= E) return;
    int sn = src[e], dn = dst[e];
    if (lane < 24) {
        float4 qv = *(const float4*)(qkv + (size_t)dn * 288 + lane * 4);
        float4 kv = *(const float4*)(qkv + (size_t)sn * 288 + 96 + lane * 4);
        *(float4*)&sQ[grp][lane * 4] = qv;
        *(float4*)&sK[grp][lane * 4] = kv;
    }
    __builtin_amdgcn_wave_barrier();
    float q0 = sQ[grp][lane * 3], q1 = sQ[grp][lane * 3 + 1], q2 = sQ[grp][lane * 3 + 2];
    float k0 = sK[grp][lane * 3], k1 = sK[grp][lane * 3 + 1], k2 = sK[grp][lane * 3 + 2];
    qk[e * 32 + lane] = (k0 * q0 + k1 * q1 + k2 * q2) * 0.5f;
}

// ---------------- bulk edge pass: ONE EDGE PER LANE, SSA vectors -----------
__global__ __launch_bounds__(256, 2) void edge_bulk_kernel(
    const float* __restrict__ edge, const float* __restrict__ qk,
    const float* __restrict__ We, const float* __restrict__ be,
    const float* __restrict__ Wb, const float* __restrict__ bb,
    const float* __restrict__ Wf0, const float* __restrict__ bf0,
    const float* __restrict__ Wf1, const float* __restrict__ bf1,
    const float* __restrict__ ge0, const float* __restrict__ be0,
    const float* __restrict__ ge1, const float* __restrict__ be1,
    float* __restrict__ exve, float* __restrict__ eout, int E)
{
    long long e = (long long)blockIdx.x * 256 + threadIdx.x;
    if (e >= E) return;

    // ---- LN(edge) -> ew ----
    v32f ev = *(const v32f*)(edge + e * 32);
    float mu = vsum32(ev) * (1.f / 32.f);
    v32f d = ev - mu;
    float var = vsum32(d * d) * (1.f / 32.f);
    float rs = rsqrtf(var + 1e-5f);
    v32f ew = d * rs * (*(const v32f*)ge0) + (*(const v32f*)be0);

    // ---- sc = qk + bb + ew@Wb ; veh = be + ew@We  (uniform rows -> SGPR) --
    v32f sc  = *(const v32f*)(qk + e * 32) + (*(const v32f*)bb);
    v32f veh = *(const v32f*)be;
    #pragma unroll
    for (int i = 0; i < 32; i++) {
        float ei = ew[i];
        sc  += ei * (*(const v32f*)(Wb + i * 32));
        veh += ei * (*(const v32f*)(We + i * 32));
    }

    // ---- exp + stream {ex, ex*ve} interleaved (16B chunks) ----
    float* xrow = exve + e * 64;
    #pragma unroll
    for (int h = 0; h < 32; h += 2) {
        float x0 = __expf(sc[h]), x1 = __expf(sc[h + 1]);
        float4 st; st.x = x0; st.y = x0 * veh[h]; st.z = x1; st.w = x1 * veh[h + 1];
        *(float4*)(xrow + h * 2) = st;
    }

    // ---- er = sc + edge ; LN -> en ----
    v32f er = sc + ev;
    float mu2 = vsum32(er) * (1.f / 32.f);
    v32f d2 = er - mu2;
    float var2 = vsum32(d2 * d2) * (1.f / 32.f);
    float rs2 = rsqrtf(var2 + 1e-5f);
    v32f en = d2 * rs2 * (*(const v32f*)ge1) + (*(const v32f*)be1);

    // ---- FFN pass 1 (outer product): F = bf0 + en @ Wf0  [64 units] ----
    v32f F0 = *(const v32f*)(bf0);
    v32f F1 = *(const v32f*)(bf0 + 32);
    #pragma unroll
    for (int i = 0; i < 32; i++) {
        float ei = en[i];
        F0 += ei * (*(const v32f*)(Wf0 + i * 64));
        F1 += ei * (*(const v32f*)(Wf0 + i * 64 + 32));
    }
    #pragma unroll
    for (int h = 0; h < 32; h++) {
        F0[h] = fmaxf(F0[h], 0.f);
        F1[h] = fmaxf(F1[h], 0.f);
    }

    // ---- FFN pass 2 (outer product): out = er + bf1 + relu(F) @ Wf1 ----
    v32f out = er + (*(const v32f*)bf1);
    #pragma unroll
    for (int j = 0; j < 32; j++) out += F0[j] * (*(const v32f*)(Wf1 + j * 32));
    #pragma unroll
    for (int j = 0; j < 32; j++) out += F1[j] * (*(const v32f*)(Wf1 + (j + 32) * 32));

    *(v32f*)(eout + e * 32) = out;
}

// ---------------- gather: one wave per node, halves process alt. edges -----
__global__ __launch_bounds__(256) void gather_kernel(
    const float* __restrict__ exve, const float* __restrict__ qkv,
    const int* __restrict__ src, const int* __restrict__ eidx,
    const int* __restrict__ off, const int* __restrict__ cnt,
    float* __restrict__ agg, int N)
{
    __shared__ float sV[4][2][96];
    __shared__ float sE[4][2][64];
    const int wave = threadIdx.x >> 6;
    const int lane = threadIdx.x & 63;
    const int head = lane & 31;
    const int half = lane >> 5;
    int n = blockIdx.x * 4 + wave;
    if (n >= N) return;
    const int o = off[n], d = cnt[n];
    float a0 = 0.f, a1 = 0.f, a2 = 0.f, a3 = 0.f, den = 0.f;
    for (int i = half; i < d; i += 2) {
        int e = eidx[o + i];
        int sn = src[e];
        const float* vr = qkv + (size_t)sn * 288 + 192;
        const float* er = exve + (size_t)e * 64;
        if (head < 24) {
            *(float4*)&sV[wave][half][head * 4] = *(const float4*)(vr + head * 4);
        } else {
            int j = head - 24;
            *(float4*)&sE[wave][half][j * 8]     = *(const float4*)(er + j * 8);
            *(float4*)&sE[wave][half][j * 8 + 4] = *(const float4*)(er + j * 8 + 4);
        }
        __builtin_amdgcn_wave_barrier();
        float ex = sE[wave][half][head * 2];
        float pv = sE[wave][half][head * 2 + 1];
        a0 += ex * sV[wave][half][head * 3];
        a1 += ex * sV[wave][half][head * 3 + 1];
        a2 += ex * sV[wave][half][head * 3 + 2];
        a3 += pv;
        den += ex;
        __builtin_amdgcn_wave_barrier();
    }
    a0 += __shfl_xor(a0, 32, 64);
    a1 += __shfl_xor(a1, 32, 64);
    a2 += __shfl_xor(a2, 32, 64);
    a3 += __shfl_xor(a3, 32, 64);
    den += __shfl_xor(den, 32, 64);
    if (half == 0) {
        float sc = (d > 0) ? 1.f / den : 0.f;
        float* ap = agg + (size_t)n * 128 + head * 4;
        ap[0] = a0 * sc; ap[1] = a1 * sc; ap[2] = a2 * sc; ap[3] = a3 * sc;
    }
}

// ---------------------------------------------------------------------------
extern "C" void kernel_launch(void* const* d_in, const int* in_sizes, int n_in,
                              void* d_out, int out_size, void* d_ws, size_t ws_size,
                              hipStream_t stream)
{
    (void)n_in; (void)out_size; (void)ws_size;
    const float* feat = (const float*)d_in[0];
    const float* edge = (const float*)d_in[1];
    const float* Wq   = (const float*)d_in[2];
    const float* bq   = (const float*)d_in[3];
    const float* Wk   = (const float*)d_in[4];
    const float* bk   = (const float*)d_in[5];
    const float* Wv   = (const float*)d_in[6];
    const float* bv   = (const float*)d_in[7];
    const float* We   = (const float*)d_in[8];
    const float* be   = (const float*)d_in[9];
    const float* Wb   = (const float*)d_in[10];
    const float* bb   = (const float*)d_in[11];
    const float* Wvv  = (const float*)d_in[12];
    const float* bvv  = (const float*)d_in[13];
    const float* Wf0  = (const float*)d_in[14];
    const float* bf0  = (const float*)d_in[15];
    const float* Wf1  = (const float*)d_in[16];
    const float* bf1  = (const float*)d_in[17];
    const float* Wm0  = (const float*)d_in[18];
    const float* bm0  = (const float*)d_in[19];
    const float* Wm1  = (const float*)d_in[20];
    const float* bm1  = (const float*)d_in[21];
    const float* g_n0 = (const float*)d_in[22];
    const float* b_n0 = (const float*)d_in[23];
    const float* g_e0 = (const float*)d_in[24];
    const float* b_e0 = (const float*)d_in[25];
    const float* g_e1 = (const float*)d_in[26];
    const float* b_e1 = (const float*)d_in[27];
    const float* g_m  = (const float*)d_in[28];
    const float* b_m  = (const float*)d_in[29];
    const float* wsc  = (const float*)d_in[30];
    const int*   src  = (const int*)d_in[31];
    const int*   dst  = (const int*)d_in[32];

    const int N = in_sizes[0] / 96;
    const int E = in_sizes[1] / 32;

    float* ws    = (float*)d_ws;
    float* qkv   = ws;                                  // N*288
    float* agg   = qkv + (size_t)N * 288;               // N*128
    float* h0    = agg + (size_t)N * 128;               // N*96 (h0, later hn)
    float* hp    = h0 + (size_t)N * 96;                 // N*96
    float* exve  = hp + (size_t)N * 96;                 // E*64
    int*   eidx  = (int*)(exve + (size_t)E * 64);       // E
    int*   cnt   = eidx + E;                            // N
    int*   offv  = cnt + N;                             // N
    int*   cur   = offv + N;                            // N
    float* tbuf  = ws;                                  // N*192, reuses qkv late
    float* hout  = (float*)d_out;
    float* eoutp = (float*)d_out + (size_t)N * 96;      // also hosts qk scores

    hipMemsetAsync(cnt, 0, (size_t)N * sizeof(int), stream);

    const int mt = (N + 63) / 64;
    const int et = (E + 255) / 256;

    // CSR bucketing (independent of node-side work)
    count_kernel<<<et, 256, 0, stream>>>(dst, cnt, E);
    scan_kernel<<<1, 1024, 0, stream>>>(cnt, offv, cur, N);
    scatter_kernel<<<et, 256, 0, stream>>>(dst, cur, eidx, E);

    // node side: h0 = LN(feat); qkv = h0 @ [Wq|Wk|Wv]
    ln96_kernel<<<(N + 7) / 8, 256, 0, stream>>>(feat, g_n0, b_n0, h0, N);
    gemm_kernel<0,0><<<dim3(mt, 2), 192, 0, stream>>>(h0, 96, Wq, 96, bq, nullptr, nullptr, qkv, 288, 0,   N, 96);
    gemm_kernel<0,0><<<dim3(mt, 2), 192, 0, stream>>>(h0, 96, Wk, 96, bk, nullptr, nullptr, qkv, 288, 96,  N, 96);
    gemm_kernel<0,0><<<dim3(mt, 2), 192, 0, stream>>>(h0, 96, Wv, 96, bv, nullptr, nullptr, qkv, 288, 192, N, 96);

    // scores -> eoutp region (qk buffer); then bulk edge pass consumes it
    score_kernel<<<(E + 7) / 8, 256, 0, stream>>>(qkv, src, dst, eoutp, E);
    edge_bulk_kernel<<<et, 256, 0, stream>>>(edge, eoutp,
                                             We, be, Wb, bb, Wf0, bf0, Wf1, bf1,
                                             g_e0, b_e0, g_e1, b_e1,
                                             exve, eoutp, E);

    // gather per node -> normalized agg[N,128]
    gather_kernel<<<(N + 3) / 4, 256, 0, stream>>>(exve, qkv, src, eidx, offv, cnt, agg, N);

    // h_pre = feat*(1+w) + agg @ Wvv + bvv
    gemm_kernel<0,1><<<dim3(mt, 2), 192, 0, stream>>>(agg, 128, Wvv, 96, bvv, feat, wsc, hp, 96, 0, N, 128);
    // hn = LN(h_pre)
    ln96_kernel<<<(N + 7) / 8, 256, 0, stream>>>(hp, g_m, b_m, h0, N);
    // t = relu(hn @ Wm0 + bm0)
    gemm_kernel<1,0><<<dim3(mt, 4), 192, 0, stream>>>(h0, 96, Wm0, 192, bm0, nullptr, nullptr, tbuf, 192, 0, N, 96);
    // h_out = h_pre + t @ Wm1 + bm1
    gemm_kernel<0,1><<<dim3(mt, 2), 192, 0, stream>>>(tbuf, 192, Wm1, 96, bm1, hp, nullptr, hout, 96, 0, N, 192);
}